// Round 7
// baseline (40.968 us; speedup 1.0000x reference)
//
#include <hip/hip_runtime.h>
#include <hip/hip_bf16.h>

// Problem constants (from reference): N=32, T=2048, C=512, V=500
#define RN 32
#define RT 2048
#define RC 512
#define RV 500

// float32(math.log(0.9))
#define LOG09 (-0.10536052f)

typedef unsigned long long ull;
typedef float v4f __attribute__((ext_vector_type(4)));

// Kernel 1: one row per block, 1024 threads (16 waves), 2 frames per thread.
// Ballot -> wave counts -> 16-lane shfl scan -> emit src_idx (+ -1 tail sentinels).
// Verified correct (rounds 5-6).
__global__ __launch_bounds__(1024)
void fr_mask_scan(const float* __restrict__ ctc,
                  const int* __restrict__ x_lens,
                  const int* __restrict__ blank_id_p,
                  int* __restrict__ src_idx,   // [N*T] in ws
                  float* __restrict__ lens_f)  // [N] tail of d_out
{
    const int n    = blockIdx.x;
    const int tid  = threadIdx.x;        // 0..1023
    const int wid  = tid >> 6;           // 0..15
    const int lane = tid & 63;
    const int blank = blank_id_p[0];
    const int xlen  = x_lens[n];

    const float* row = ctc + (size_t)n * RT * RV + blank;

    // Wave wid owns frames [wid*128, wid*128+128): t0 = +lane, t1 = +64+lane.
    const int t0 = wid * 128 + lane;
    const int t1 = t0 + 64;
    const bool k0 = (t0 < xlen) && (row[(size_t)t0 * RV] < LOG09);
    const bool k1 = (t1 < xlen) && (row[(size_t)t1 * RV] < LOG09);
    const ull w0 = __ballot(k0);
    const ull w1 = __ballot(k1);
    const int c0 = __popcll(w0);
    const int wcnt = c0 + __popcll(w1);

    __shared__ int sh_cnt[16];
    __shared__ int sh_excl[16];
    __shared__ int sh_total;

    if (lane == 0) sh_cnt[wid] = wcnt;
    __syncthreads();
    if (tid < 16) {
        int incl = sh_cnt[tid];
#pragma unroll
        for (int off = 1; off < 16; off <<= 1) {
            int v = __shfl_up(incl, off, 64);
            if (tid >= off) incl += v;
        }
        sh_excl[tid] = incl - sh_cnt[tid];
        if (tid == 15) sh_total = incl;
    }
    __syncthreads();

    const int total = sh_total;
    int* srow = src_idx + n * RT;

    // Emit kept frame indices (positions < total).
    const ull ltmask = ((ull)1 << lane) - 1;  // lanes below
    const int base = sh_excl[wid];
    if (k0) srow[base + __popcll(w0 & ltmask)] = t0;
    if (k1) srow[base + c0 + __popcll(w1 & ltmask)] = t1;

    // -1 sentinels for positions >= total (disjoint from emission range).
    if (t0 >= total) srow[t0] = -1;
    if (t1 >= total) srow[t1] = -1;

    if (tid == 0) lens_f[n] = (float)total;  // harness reads output as f32
}

// Kernel 2: round-6 gather structure exactly; ONLY change = nontemporal
// load/store (zero-reuse streams; bypass cache allocation).
// 32768 blocks x 256 threads; each half-block (128 lanes x 16B) moves one
// full 2 KB output row in a single load + single store.
__global__ __launch_bounds__(256)
void fr_gather(const float* __restrict__ x,
               const int* __restrict__ src_idx,
               v4f* __restrict__ out)
{
    const int r    = blockIdx.x * 2 + (threadIdx.x >> 7);  // output row in [0, N*T)
    const int lane = threadIdx.x & 127;
    const int n = r >> 11;                                  // / T

    const int t = src_idx[r];   // broadcast
    v4f v = (v4f)(0.f);
    if (t >= 0) {               // wave-uniform branch
        const v4f* xr = (const v4f*)x + ((size_t)((n << 11) | t)) * (RC / 4);
        v = __builtin_nontemporal_load(&xr[lane]);
    }
    __builtin_nontemporal_store(v, &out[(size_t)r * (RC / 4) + lane]);
}

extern "C" void kernel_launch(void* const* d_in, const int* in_sizes, int n_in,
                              void* d_out, int out_size, void* d_ws, size_t ws_size,
                              hipStream_t stream) {
    const float* x        = (const float*)d_in[0];   // [N, T, C] f32
    const int*   x_lens   = (const int*)d_in[1];     // [N] int32
    const float* ctc      = (const float*)d_in[2];   // [N, T, V] f32
    const int*   blank_id = (const int*)d_in[3];     // scalar

    float* out    = (float*)d_out;                   // [N*T*C] + [N] lens (as f32)
    float* lens_f = out + (size_t)RN * RT * RC;

    int* src_idx = (int*)d_ws;                       // [N*T]

    fr_mask_scan<<<RN, 1024, 0, stream>>>(ctc, x_lens, blank_id, src_idx, lens_f);
    fr_gather<<<(RN * RT) / 2, 256, 0, stream>>>(x, src_idx, (v4f*)out);
}

// Round 8
// 32.721 us; speedup vs baseline: 1.2520x; 1.2520x over previous
//
#include <hip/hip_runtime.h>
#include <hip/hip_bf16.h>

// Problem constants (from reference): N=32, T=2048, C=512, V=500
#define RN 32
#define RT 2048
#define RC 512
#define RV 500

// float32(math.log(0.9))
#define LOG09 (-0.10536052f)

typedef unsigned long long ull;
typedef float v4f __attribute__((ext_vector_type(4)));

// Kernel 1: one row per block, 1024 threads (16 waves), 2 frames per thread.
// Ballot -> wave counts -> 16-lane shfl scan -> emit src_idx (+ -1 tail sentinels).
// Verified correct (rounds 5-7).
__global__ __launch_bounds__(1024)
void fr_mask_scan(const float* __restrict__ ctc,
                  const int* __restrict__ x_lens,
                  const int* __restrict__ blank_id_p,
                  int* __restrict__ src_idx,   // [N*T] in ws
                  float* __restrict__ lens_f)  // [N] tail of d_out
{
    const int n    = blockIdx.x;
    const int tid  = threadIdx.x;        // 0..1023
    const int wid  = tid >> 6;           // 0..15
    const int lane = tid & 63;
    const int blank = blank_id_p[0];
    const int xlen  = x_lens[n];

    const float* row = ctc + (size_t)n * RT * RV + blank;

    // Wave wid owns frames [wid*128, wid*128+128): t0 = +lane, t1 = +64+lane.
    const int t0 = wid * 128 + lane;
    const int t1 = t0 + 64;
    const bool k0 = (t0 < xlen) && (row[(size_t)t0 * RV] < LOG09);
    const bool k1 = (t1 < xlen) && (row[(size_t)t1 * RV] < LOG09);
    const ull w0 = __ballot(k0);
    const ull w1 = __ballot(k1);
    const int c0 = __popcll(w0);
    const int wcnt = c0 + __popcll(w1);

    __shared__ int sh_cnt[16];
    __shared__ int sh_excl[16];
    __shared__ int sh_total;

    if (lane == 0) sh_cnt[wid] = wcnt;
    __syncthreads();
    if (tid < 16) {
        int incl = sh_cnt[tid];
#pragma unroll
        for (int off = 1; off < 16; off <<= 1) {
            int v = __shfl_up(incl, off, 64);
            if (tid >= off) incl += v;
        }
        sh_excl[tid] = incl - sh_cnt[tid];
        if (tid == 15) sh_total = incl;
    }
    __syncthreads();

    const int total = sh_total;
    int* srow = src_idx + n * RT;

    // Emit kept frame indices (positions < total).
    const ull ltmask = ((ull)1 << lane) - 1;  // lanes below
    const int base = sh_excl[wid];
    if (k0) srow[base + __popcll(w0 & ltmask)] = t0;
    if (k1) srow[base + c0 + __popcll(w1 & ltmask)] = t1;

    // -1 sentinels for positions >= total (disjoint from emission range).
    if (t0 >= total) srow[t0] = -1;
    if (t1 >= total) srow[t1] = -1;

    if (tid == 0) lens_f[n] = (float)total;  // harness reads output as f32
}

// Kernel 2: flat streaming gather (best measured structure, round 6).
// 32768 blocks x 256 threads; each half-block (128 lanes x 16B) moves one
// full 2 KB output row in a single load + single store. Plain (cached)
// loads/stores — nontemporal measured +7.9 us slower on gfx950 (round 7).
__global__ __launch_bounds__(256)
void fr_gather(const float* __restrict__ x,
               const int* __restrict__ src_idx,
               v4f* __restrict__ out)
{
    const int r    = blockIdx.x * 2 + (threadIdx.x >> 7);  // output row in [0, N*T)
    const int lane = threadIdx.x & 127;
    const int n = r >> 11;                                  // / T

    const int t = src_idx[r];   // broadcast
    v4f v = (v4f)(0.f);
    if (t >= 0) {               // wave-uniform branch
        const v4f* xr = (const v4f*)x + ((size_t)((n << 11) | t)) * (RC / 4);
        v = xr[lane];
    }
    out[(size_t)r * (RC / 4) + lane] = v;
}

extern "C" void kernel_launch(void* const* d_in, const int* in_sizes, int n_in,
                              void* d_out, int out_size, void* d_ws, size_t ws_size,
                              hipStream_t stream) {
    const float* x        = (const float*)d_in[0];   // [N, T, C] f32
    const int*   x_lens   = (const int*)d_in[1];     // [N] int32
    const float* ctc      = (const float*)d_in[2];   // [N, T, V] f32
    const int*   blank_id = (const int*)d_in[3];     // scalar

    float* out    = (float*)d_out;                   // [N*T*C] + [N] lens (as f32)
    float* lens_f = out + (size_t)RN * RT * RC;

    int* src_idx = (int*)d_ws;                       // [N*T]

    fr_mask_scan<<<RN, 1024, 0, stream>>>(ctc, x_lens, blank_id, src_idx, lens_f);
    fr_gather<<<(RN * RT) / 2, 256, 0, stream>>>(x, src_idx, (v4f*)out);
}